// Round 1
// 306.060 us; speedup vs baseline: 1.0343x; 1.0343x over previous
//
#include <hip/hip_runtime.h>
#include <math.h>

// Problem constants
constexpr int ROWS  = 19456;   // B*C*N = 16*19*64
constexpr int IN_DIM = 200;
constexpr int FREQ  = 101;     // rfft bins
constexpr int VQD   = 64;
constexpr int NEMB  = 8192;
constexpr int DFT_BLOCKS = ROWS / 8;   // 2432

typedef __attribute__((ext_vector_type(8))) short short8;   // 8 bf16 = 4 VGPRs
typedef __attribute__((ext_vector_type(4))) float floatx4;

__device__ __forceinline__ unsigned short f2bf(float v) {   // RTN-even fp32->bf16
    unsigned int u = __builtin_bit_cast(unsigned int, v);
    unsigned int r = u + 0x7fffu + ((u >> 16) & 1u);
    return (unsigned short)(r >> 16);
}
__device__ __forceinline__ float bf2f(unsigned short b) {
    unsigned int u = ((unsigned int)b) << 16;
    return __builtin_bit_cast(float, u);
}

// cis(-2*pi*r/200) with exact quarter points (bitwise-identical to the r1-validated table)
__device__ __forceinline__ void cis_exact(int r, double& c, double& s) {
    if (r == 0)        { c =  1.0; s =  0.0; }
    else if (r == 50)  { c =  0.0; s = -1.0; }
    else if (r == 100) { c = -1.0; s =  0.0; }
    else if (r == 150) { c =  0.0; s =  1.0; }
    else {
        double ang = -6.283185307179586476925286766559 * (double)r / (double)IN_DIM;
        c = cos(ang); s = sin(ang);
    }
}

// async global->LDS DMA, 16 B per lane; LDS dest = wave-uniform base + lane*16
#define GLOAD_LDS(gp, lp) __builtin_amdgcn_global_load_lds( \
    (const __attribute__((address_space(1))) unsigned int*)(gp), \
    (__attribute__((address_space(3))) unsigned int*)(lp), 16, 0, 0)

// ---------------- workspace layout ----------------
constexpr size_t align256(size_t x) { return (x + 255) & ~(size_t)255; }
constexpr size_t SZ_FB    = (size_t)2 * ROWS * VQD * sizeof(unsigned short); // bf16 feats [2][ROWS][64]
constexpr size_t OFF_FTH  = 0;
constexpr size_t OFF_FTL  = align256(OFF_FTH + SZ_FB);
constexpr size_t SZ_CBB   = (size_t)2 * NEMB * VQD * sizeof(unsigned short); // bf16 codes [2][8192][64]
constexpr size_t OFF_CBH  = align256(OFF_FTL + SZ_FB);
constexpr size_t OFF_CBL  = align256(OFF_CBH + SZ_CBB);
constexpr size_t SZ_FD    = (size_t)2 * ROWS * VQD * sizeof(double);         // f64 feats
constexpr size_t OFF_FD   = align256(OFF_CBL + SZ_CBB);
constexpr size_t SZ_INV   = (size_t)2 * NEMB * sizeof(double);               // f64 1/||cb||
constexpr size_t OFF_INV  = align256(OFF_FD + SZ_FD);
constexpr size_t SZ_PI    = (size_t)2 * 4 * ROWS * sizeof(int);              // top-2 per 2048-chunk
constexpr size_t OFF_PI1  = align256(OFF_INV + SZ_INV);
constexpr size_t OFF_PI2  = align256(OFF_PI1 + SZ_PI);

// ---------------- 1. fused DFT/proj (blocks < 2432) + cb_prep (blocks >= 2432) ----------------
// r18: f32 DFT rework. The f64 pipeline cost ~4-cyc f64 VALU everywhere + ~80-op f64 atan2
// + 32 KB LDS (5 blocks/CU). New scheme:
//   - f32 pair-sums, f32 FMA accumulation (noise ~5e-6 abs, |X|rms ~ 10)
//   - twiddle recurrence KEPT in f64 (f32 recurrence drifts n*2^-24 -> 2e-4 phase error)
//   - amp/phase in f32 (sqrtf/atan2f) with EXACT-f64 per-bin fallback when amp^2 < 0.04
//     (amp < 0.014*rms; ~400 of 1.96M bins; caps phase error at 2.5e-5 rad globally)
//   - projection in f32; featD = f64 upcast of the f32 feature (rescore ranks exactly)
//   - bins k=0,100 keep im == +0 exactly (f64 recurrence holds ws at +-0) -> phase 0/pi
//     identical to the validated f64 path
// LDS plan (20064 B, disjoint; no r17-style parking):
//   [    0,  7200) xsT f32 [n=200][r] stride 9 (pad kills 16-way transpose-write conflict)
//   [ 7200, 10400) xp  f32 [n][8] n=1..99
//   [10400, 13600) xm  f32
//   [13600, 16832) reS f32 [k][8]: half-1 partials -> final re -> amp
//   [16832, 20064) imS f32 [k][8]: half-1 partials -> final im -> phase
//   projection phase: accS f32 [128][8] aliases xp base (xp/xm dead after main loop)
__global__ __launch_bounds__(256) void dft_cb_kernel(
    const float* __restrict__ x, const float* __restrict__ projA, const float* __restrict__ projP,
    const float* __restrict__ cbA, const float* __restrict__ cbP,
    unsigned short* __restrict__ ftH, unsigned short* __restrict__ ftL, double* __restrict__ featD,
    unsigned short* __restrict__ cbH, unsigned short* __restrict__ cbL, double* __restrict__ invnD)
{
    __shared__ __align__(16) char smem[20064];
    const int tid = threadIdx.x;

    if (blockIdx.x >= DFT_BLOCKS) {
        // ---- cb_prep body (validated rounds 5-16, unchanged) ----
        float* tile = (float*)smem;            // 64*65*4 = 16640 B
        float* inv  = (float*)(smem + 16640);  // 256 B
        const int bid2 = blockIdx.x - DFT_BLOCKS;
        const int which = bid2 >> 7;
        const int m0 = (bid2 & 127) * 64;
        const float* cb = which ? cbP : cbA;
        for (int e = tid; e < 4096; e += 256) {
            int c = e >> 6, d = e & 63;
            tile[c * 65 + d] = cb[(size_t)(m0 + c) * VQD + d];
        }
        __syncthreads();
        if (tid < 64) {
            double s = 0.0;
            for (int d2 = 0; d2 < 64; ++d2) { double v = (double)tile[tid * 65 + d2]; s += v * v; }
            inv[tid] = (float)(1.0 / sqrt(s));
            invnD[(size_t)which * NEMB + m0 + tid] = 1.0 / sqrt(s);
        }
        __syncthreads();
        for (int e = tid; e < 4096; e += 256) {
            int c = e >> 6, d = e & 63;
            float v = tile[c * 65 + d] * inv[c];
            unsigned short hb = f2bf(v);
            unsigned short lb = f2bf(v - bf2f(hb));
            size_t o = ((size_t)which * NEMB + m0 + c) * VQD + d;
            cbH[o] = hb; cbL[o] = lb;
        }
        return;
    }

    float* xsT  = (float*)smem;                 // [n][r] stride 9
    float* xpS  = (float*)(smem + 7200);        // [n][8], n=1..99
    float* xmS  = (float*)(smem + 10400);
    float* reS  = (float*)(smem + 13600);       // [k][8]
    float* imS  = (float*)(smem + 16832);
    float* accS = (float*)(smem + 7200);        // proj partials, after xp/xm die
    const int r0 = blockIdx.x * 8;

    for (int e = tid; e < 8 * IN_DIM; e += 256) {
        int r = e / IN_DIM, n = e - r * IN_DIM;
        xsT[n * 9 + r] = x[(size_t)(r0 + r) * IN_DIM + n];
    }
    __syncthreads();

    // pair build in f32: xp = x[n]+x[200-n], xm = x[n]-x[200-n] (rounding ~2^-25, in budget)
    for (int e = tid; e < 99 * 8; e += 256) {
        int n = (e >> 3) + 1, r = e & 7;
        float a = xsT[n * 9 + r];
        float b = xsT[(IN_DIM - n) * 9 + r];
        xpS[n * 8 + r] = a + b;
        xmS[n * 8 + r] = a - b;
    }
    __syncthreads();

    const int k = tid & 127, half = tid >> 7;
    float re[8], im[8];
    if (k < FREQ) {
        double c1, s1;
        cis_exact(k, c1, s1);                        // step multiplier (f64, drift-free)
        const int n0 = half ? 51 : 1;
        double wc, ws;
        cis_exact((int)(((long long)k * n0) % IN_DIM), wc, ws);   // start twiddle
#pragma unroll
        for (int r = 0; r < 8; ++r) { re[r] = 0.f; im[r] = 0.f; }
        if (half) {
            // singles n=0 (w=1) and n=100 (w=((-1)^k,+0)); im contribution exactly +-0 -> skip
            float sg = (k & 1) ? -1.f : 1.f;
#pragma unroll
            for (int r = 0; r < 8; ++r)
                re[r] = xsT[r] + sg * xsT[100 * 9 + r];
        }
        const int nEnd = half ? 100 : 51;            // half0: 1..50, half1: 51..99
        for (int n = n0; n < nEnd; ++n) {
            const float* xpn = xpS + n * 8;
            const float* xmn = xmS + n * 8;
            float wcf = (float)wc, wsf = (float)ws;
#pragma unroll
            for (int r = 0; r < 8; ++r) {
                re[r] = fmaf(xpn[r], wcf, re[r]);
                im[r] = fmaf(xmn[r], wsf, im[r]);
            }
            double nwc = fma(wc, c1, -ws * s1);
            double nws = fma(wc, s1,  ws * c1);
            wc = nwc; ws = nws;
        }
        if (half) {
#pragma unroll
            for (int r = 0; r < 8; ++r) { reS[k * 8 + r] = re[r]; imS[k * 8 + r] = im[r]; }
        }
    }
    __syncthreads();
    // combine halves in-place (each [k][r] owned by exactly one half-0 thread)
    if (half == 0 && k < FREQ) {
#pragma unroll
        for (int r = 0; r < 8; ++r) {
            re[r] += reS[k * 8 + r]; im[r] += imS[k * 8 + r];
            reS[k * 8 + r] = re[r];  imS[k * 8 + r] = im[r];
        }
    }
    __syncthreads();
    // amp/phase on ALL 256 threads, f32 fast path; rare exact-f64 fallback for small bins
    // (xsT still alive -> fallback recomputes the bin from the exact f32 inputs)
    for (int e = tid; e < FREQ * 8; e += 256) {
        float c = reS[e], s = imS[e];
        float a2 = fmaf(c, c, s * s);
        float ampv, phv;
        if (a2 >= 0.04f) {
            ampv = sqrtf(a2);
            phv  = atan2f(s, c);
        } else {
            const int kk = e >> 3, rr = e & 7;
            double sg = (kk & 1) ? -1.0 : 1.0;
            double reD = (double)xsT[rr] + sg * (double)xsT[100 * 9 + rr];
            double imD = 0.0;
            double c1, s1;
            cis_exact(kk, c1, s1);
            double wc = c1, ws = s1;                 // w at n=1
            for (int n = 1; n < 100; ++n) {
                double a = (double)xsT[n * 9 + rr];
                double b = (double)xsT[(IN_DIM - n) * 9 + rr];
                reD = fma(a + b, wc, reD);
                imD = fma(a - b, ws, imD);
                double nwc = fma(wc, c1, -ws * s1);
                double nws = fma(wc, s1,  ws * c1);
                wc = nwc; ws = nws;
            }
            ampv = (float)sqrt(reD * reD + imD * imD);
            phv  = (float)atan2(imD, reD);
        }
        reS[e] = ampv; imS[e] = phv;
    }
    __syncthreads();

    // projection in f32: d = tid&63; which = amp/phase; grp splits kk range 51/50
    const int d = tid & 63, which = (tid >> 6) & 1, grp = tid >> 7;
    const float* proj = which ? projP : projA;
    const float* srcF = which ? imS : reS;          // [k][8], k-major
    float acc[8];
#pragma unroll
    for (int r = 0; r < 8; ++r) acc[r] = 0.f;
    const int kkA = grp ? 51 : 0;
    const int kkB = grp ? FREQ : 51;
    for (int kk = kkA; kk < kkB; ++kk) {
        float p = proj[kk * VQD + d];
#pragma unroll
        for (int r = 0; r < 8; ++r) acc[r] = fmaf(srcF[kk * 8 + r], p, acc[r]);
    }
    if (grp) {
#pragma unroll
        for (int r = 0; r < 8; ++r) accS[(tid & 127) * 8 + r] = acc[r];
    }
    __syncthreads();
    if (grp == 0) {
#pragma unroll
        for (int r = 0; r < 8; ++r) acc[r] += accS[tid * 8 + r];
#pragma unroll
        for (int r = 0; r < 8; ++r) {
            size_t rowi = (size_t)which * ROWS + r0 + r;
            float vf = acc[r];
            unsigned short hb = f2bf(vf);
            unsigned short lb = f2bf(vf - bf2f(hb));
            ftH[rowi * VQD + d] = hb;
            ftL[rowi * VQD + d] = lb;
            featD[rowi * VQD + d] = (double)acc[r];
        }
    }
}

// ---------------- 2. bf16x3 MFMA sim + top-2, DMA double-buffered prefetch ----------------
// (round-10 version, byte-identical: best measured; argmax is closed at ~154 us — MFMA
// pipe at the bf16x3 algorithmic floor, selection VALU near op-count floor, residual
// idle resisted 4 structural attacks)
#define MFMA(a, b, c) __builtin_amdgcn_mfma_f32_16x16x32_bf16(a, b, c, 0, 0, 0)
#define UPD(val, s) do { float _v = (val); \
    bool _c1 = _v > b1v[s]; bool _c2 = _v > b2v[s]; \
    b2v[s] = _c1 ? b1v[s] : (_c2 ? _v : b2v[s]); \
    b2i[s] = _c1 ? b1i[s] : (_c2 ? idx : b2i[s]); \
    b1v[s] = _c1 ? _v : b1v[s]; \
    b1i[s] = _c1 ? idx : b1i[s]; } while (0)

__global__ __launch_bounds__(256, 3) void argmax_kernel(
    const unsigned short* __restrict__ ftH, const unsigned short* __restrict__ ftL,
    const unsigned short* __restrict__ cbH, const unsigned short* __restrict__ cbL,
    int* __restrict__ pi1, int* __restrict__ pi2)
{
    __shared__ __align__(16) char lds[33792];
    const int tid = threadIdx.x;
    const int f = blockIdx.y, z = blockIdx.z;
    const int r0 = blockIdx.x * 128;
    const int w = tid >> 6, lane = tid & 63;
    const int q = lane >> 4, cl = lane & 15;

    const unsigned short* ftHb = ftH + (size_t)f * ROWS * VQD;
    const unsigned short* ftLb = ftL + (size_t)f * ROWS * VQD;
    const unsigned short* cbHb = cbH + (size_t)f * NEMB * VQD;
    const unsigned short* cbLb = cbL + (size_t)f * NEMB * VQD;

    short8 aH00, aH01, aH10, aH11, aL00, aL01, aL10, aL11;
    {
        const size_t baseA = (size_t)(r0 + w * 32 + cl) * VQD + q * 8;
        const size_t baseB = baseA + (size_t)16 * VQD;
        aH00 = *(const short8*)(ftHb + baseA);
        aH01 = *(const short8*)(ftHb + baseA + 32);
        aH10 = *(const short8*)(ftHb + baseB);
        aH11 = *(const short8*)(ftHb + baseB + 32);
        aL00 = *(const short8*)(ftLb + baseA);
        aL01 = *(const short8*)(ftLb + baseA + 32);
        aL10 = *(const short8*)(ftLb + baseB);
        aL11 = *(const short8*)(ftLb + baseB + 32);
    }

    float b1v[8], b2v[8]; int b1i[8], b2i[8];
#pragma unroll
    for (int s = 0; s < 8; ++s) { b1v[s] = -INFINITY; b2v[s] = -INFINITY; b1i[s] = 0; b2i[s] = 0; }

    const int cBase = tid >> 3;
    const int jel   = (((tid & 7) ^ (cBase & 7)) << 3);
    const unsigned short* gH = cbHb + (size_t)(z * 2048 + cBase) * VQD + jel;
    const unsigned short* gL = cbLb + (size_t)(z * 2048 + cBase) * VQD + jel;

    const int p0 = ((q ^ (cl & 7)) << 4);
    const int p1 = p0 ^ 64;

#pragma unroll
    for (int r = 0; r < 2; ++r) {
        const size_t gofs = (size_t)(32 * r) * VQD;
        GLOAD_LDS(gH + gofs, lds + w * 1024 + r * 4096);
        GLOAD_LDS(gL + gofs, lds + 8192 + w * 1024 + r * 4096);
    }

    for (int it = 0; it < 32; ++it) {
        __syncthreads();
        if (it < 31) {
            char* nbuf = lds + ((it + 1) & 1) * 16384;
            const size_t gbase = (size_t)((it + 1) * 64) * VQD;
#pragma unroll
            for (int r = 0; r < 2; ++r) {
                const size_t gofs = gbase + (size_t)(32 * r) * VQD;
                GLOAD_LDS(gH + gofs, nbuf + w * 1024 + r * 4096);
                GLOAD_LDS(gL + gofs, nbuf + 8192 + w * 1024 + r * 4096);
            }
        }

        const char* buf = lds + (it & 1) * 16384;
        const int cbase = z * 2048 + it * 64;
#pragma unroll
        for (int nt = 0; nt < 4; ++nt) {
            const char* row = buf + (nt * 16 + cl) * 128;
            short8 bH0 = *(const short8*)(row + p0);
            short8 bH1 = *(const short8*)(row + p1);
            short8 bL0 = *(const short8*)(row + 8192 + p0);
            short8 bL1 = *(const short8*)(row + 8192 + p1);

            floatx4 acc0 = {0.f, 0.f, 0.f, 0.f};
            floatx4 acc1 = {0.f, 0.f, 0.f, 0.f};
            acc0 = MFMA(aH00, bH0, acc0);  acc1 = MFMA(aH10, bH0, acc1);
            acc0 = MFMA(aH01, bH1, acc0);  acc1 = MFMA(aH11, bH1, acc1);
            acc0 = MFMA(aH00, bL0, acc0);  acc1 = MFMA(aH10, bL0, acc1);
            acc0 = MFMA(aH01, bL1, acc0);  acc1 = MFMA(aH11, bL1, acc1);
            acc0 = MFMA(aL00, bH0, acc0);  acc1 = MFMA(aL10, bH0, acc1);
            acc0 = MFMA(aL01, bH1, acc0);  acc1 = MFMA(aL11, bH1, acc1);

            const int idx = cbase + nt * 16 + cl;
#pragma unroll
            for (int i = 0; i < 4; ++i) { UPD(acc0[i], i); UPD(acc1[i], 4 + i); }
        }
    }

    __syncthreads();
    float* redv = (float*)lds;           // [128][33]
    int*   redi = (int*)(lds + 128 * 33 * 4);
#pragma unroll
    for (int s = 0; s < 8; ++s) {
        int rowl = w * 32 + ((s & 4) << 2) + q * 4 + (s & 3);   // +16 when s>=4
        int base = rowl * 33 + cl * 2;
        redv[base]     = b1v[s]; redi[base]     = b1i[s];
        redv[base + 1] = b2v[s]; redi[base + 1] = b2i[s];
    }
    __syncthreads();
    if (tid < 128) {
        float v1 = -INFINITY, v2 = -INFINITY; int i1 = 0x7fffffff, i2 = 0x7fffffff;
        for (int e = 0; e < 32; ++e) {
            float v = redv[tid * 33 + e]; int id = redi[tid * 33 + e];
            if (v > v1 || (v == v1 && id < i1)) { v2 = v1; i2 = i1; v1 = v; i1 = id; }
            else if (v > v2 || (v == v2 && id < i2)) { v2 = v; i2 = id; }
        }
        size_t p = ((size_t)(f * 4 + z)) * ROWS + r0 + tid;
        pi1[p] = i1; pi2[p] = i2;
    }
}

// ---------------- 3. f64 rescore of the 8 candidates/row (round-5 version) ----------------
__global__ __launch_bounds__(256) void rescore_kernel(
    const double* __restrict__ featD, const double* __restrict__ invnD,
    const float* __restrict__ cbA, const float* __restrict__ cbP,
    const int* __restrict__ pi1, const int* __restrict__ pi2,
    int* __restrict__ out)
{
    const int tid = threadIdx.x;
    const int lane = tid & 63, wave = tid >> 6;
    const int task = blockIdx.x * 4 + wave;           // 0 .. 2*ROWS-1
    const int f = task / ROWS;
    const int row = task - f * ROWS;
    const float* cb = f ? cbP : cbA;
    const double fd = featD[((size_t)f * ROWS + row) * VQD + lane];

    int idxs[8];
#pragma unroll
    for (int c = 0; c < 8; ++c) {
        int zz = c >> 1;
        size_t p = ((size_t)(f * 4 + zz)) * ROWS + row;
        idxs[c] = (c & 1) ? pi2[p] : pi1[p];
    }
    double cv[8];
#pragma unroll
    for (int c = 0; c < 8; ++c)
        cv[c] = (double)cb[(size_t)idxs[c] * VQD + lane];

    double bestv = -1.0e300; int besti = 0x7fffffff;
#pragma unroll
    for (int c = 0; c < 8; ++c) {
        double t = fd * cv[c];
        for (int m = 32; m >= 1; m >>= 1) t += __shfl_xor(t, m, 64);
        double sim = t * invnD[(size_t)f * NEMB + idxs[c]];
        int idx = idxs[c];
        if (sim > bestv || (sim == bestv && idx < besti)) { bestv = sim; besti = idx; }
    }
    if (lane == 0) out[task] = besti;
}

// ---------------- launch ----------------
extern "C" void kernel_launch(void* const* d_in, const int* in_sizes, int n_in,
                              void* d_out, int out_size, void* d_ws, size_t ws_size,
                              hipStream_t stream)
{
    const float* x     = (const float*)d_in[0];
    const float* projA = (const float*)d_in[1];
    const float* projP = (const float*)d_in[2];
    const float* cbA   = (const float*)d_in[3];
    const float* cbP   = (const float*)d_in[4];

    char* ws = (char*)d_ws;
    unsigned short* ftH   = (unsigned short*)(ws + OFF_FTH);
    unsigned short* ftL   = (unsigned short*)(ws + OFF_FTL);
    unsigned short* cbHp  = (unsigned short*)(ws + OFF_CBH);
    unsigned short* cbLp  = (unsigned short*)(ws + OFF_CBL);
    double*         featD = (double*)(ws + OFF_FD);
    double*         invnD = (double*)(ws + OFF_INV);
    int*            pi1   = (int*)(ws + OFF_PI1);
    int*            pi2   = (int*)(ws + OFF_PI2);

    dft_cb_kernel<<<DFT_BLOCKS + 256, 256, 0, stream>>>(
        x, projA, projP, cbA, cbP, ftH, ftL, featD, cbHp, cbLp, invnD);
    argmax_kernel<<<dim3(ROWS / 128, 2, 4), 256, 0, stream>>>(ftH, ftL, cbHp, cbLp, pi1, pi2);
    rescore_kernel<<<(2 * ROWS) / 4, 256, 0, stream>>>(featD, invnD, cbA, cbP, pi1, pi2, (int*)d_out);
}

// Round 2
// 276.130 us; speedup vs baseline: 1.1464x; 1.1084x over previous
//
#include <hip/hip_runtime.h>
#include <math.h>

// Problem constants
constexpr int ROWS  = 19456;   // B*C*N = 16*19*64
constexpr int IN_DIM = 200;
constexpr int FREQ  = 101;     // rfft bins
constexpr int VQD   = 64;
constexpr int NEMB  = 8192;
constexpr int DFT_BLOCKS = ROWS / 8;   // 2432

typedef __attribute__((ext_vector_type(8))) short short8;   // 8 bf16 = 4 VGPRs
typedef __attribute__((ext_vector_type(4))) float floatx4;

__device__ __forceinline__ unsigned short f2bf(float v) {   // RTN-even fp32->bf16
    unsigned int u = __builtin_bit_cast(unsigned int, v);
    unsigned int r = u + 0x7fffu + ((u >> 16) & 1u);
    return (unsigned short)(r >> 16);
}
__device__ __forceinline__ float bf2f(unsigned short b) {
    unsigned int u = ((unsigned int)b) << 16;
    return __builtin_bit_cast(float, u);
}

// cis(-2*pi*r/200) with exact quarter points (bitwise-identical to the r1-validated table)
__device__ __forceinline__ void cis_exact(int r, double& c, double& s) {
    if (r == 0)        { c =  1.0; s =  0.0; }
    else if (r == 50)  { c =  0.0; s = -1.0; }
    else if (r == 100) { c = -1.0; s =  0.0; }
    else if (r == 150) { c =  0.0; s =  1.0; }
    else {
        double ang = -6.283185307179586476925286766559 * (double)r / (double)IN_DIM;
        c = cos(ang); s = sin(ang);
    }
}

// async global->LDS DMA, 16 B per lane; LDS dest = wave-uniform base + lane*16
#define GLOAD_LDS(gp, lp) __builtin_amdgcn_global_load_lds( \
    (const __attribute__((address_space(1))) unsigned int*)(gp), \
    (__attribute__((address_space(3))) unsigned int*)(lp), 16, 0, 0)

// ---------------- workspace layout ----------------
constexpr size_t align256(size_t x) { return (x + 255) & ~(size_t)255; }
constexpr size_t SZ_FB    = (size_t)2 * ROWS * VQD * sizeof(unsigned short); // bf16 feats [2][ROWS][64]
constexpr size_t OFF_FTH  = 0;
constexpr size_t OFF_FTL  = align256(OFF_FTH + SZ_FB);
constexpr size_t SZ_CBB   = (size_t)2 * NEMB * VQD * sizeof(unsigned short); // bf16 codes [2][8192][64]
constexpr size_t OFF_CBH  = align256(OFF_FTL + SZ_FB);
constexpr size_t OFF_CBL  = align256(OFF_CBH + SZ_CBB);
constexpr size_t SZ_FD    = (size_t)2 * ROWS * VQD * sizeof(double);         // f64 feats
constexpr size_t OFF_FD   = align256(OFF_CBL + SZ_CBB);
constexpr size_t SZ_INV   = (size_t)2 * NEMB * sizeof(double);               // f64 1/||cb||
constexpr size_t OFF_INV  = align256(OFF_FD + SZ_FD);
constexpr size_t SZ_PI    = (size_t)2 * 4 * ROWS * sizeof(int);              // top-2 per 2048-chunk
constexpr size_t OFF_PI1  = align256(OFF_INV + SZ_INV);
constexpr size_t OFF_PI2  = align256(OFF_PI1 + SZ_PI);

// ---------------- 1. fused DFT/proj (blocks < 2432) + cb_prep (blocks >= 2432) ----------------
// r19: kill the f64-sincos tax. r18 kept cis_exact (OCML f64 sincos, ~10^2 ops, divergent)
// called 2x by EVERY thread = 8 wave-calls/block. Now:
//   - threads k<101 compute cis_exact(k) ONCE into an LDS table cisT (2 wave-calls/block)
//   - all threads read (c1,s1) from the table
//   - half-1 start twiddle cis(51k) = cis(50k)*cis(k); 50k mod 200 is an EXACT quarter
//     point selected by k&3 -> pure sign/swap of (c1,s1), no second sincos.
//     (k=0/100 im==+0 invariant verified: step stays exact {0,+-1}; +0 + -0 = +0 RTN.)
//   - cisT aliases the reS region (dead until half-1's post-loop stores); an extra
//     top-level barrier after the table read seals it. LDS stays 20064 B = 8 blocks/CU.
// LDS plan (20064 B):
//   [    0,  7200) xsT f32 [n=200][r] stride 9 (pad kills 16-way transpose-write conflict)
//   [ 7200, 10400) xp  f32 [n][8] n=1..99
//   [10400, 13600) xm  f32
//   [13600, 16832) reS f32 [k][8]: cisT (f64[101][2], 1616 B) -> half-1 re -> final re -> amp
//   [16832, 20064) imS f32 [k][8]: half-1 im -> final im -> phase
//   projection phase: accS f32 [128][8] aliases xp base (xp/xm dead after main loop)
__global__ __launch_bounds__(256) void dft_cb_kernel(
    const float* __restrict__ x, const float* __restrict__ projA, const float* __restrict__ projP,
    const float* __restrict__ cbA, const float* __restrict__ cbP,
    unsigned short* __restrict__ ftH, unsigned short* __restrict__ ftL, double* __restrict__ featD,
    unsigned short* __restrict__ cbH, unsigned short* __restrict__ cbL, double* __restrict__ invnD)
{
    __shared__ __align__(16) char smem[20064];
    const int tid = threadIdx.x;

    if (blockIdx.x >= DFT_BLOCKS) {
        // ---- cb_prep body (validated rounds 5-16, unchanged) ----
        float* tile = (float*)smem;            // 64*65*4 = 16640 B
        float* inv  = (float*)(smem + 16640);  // 256 B
        const int bid2 = blockIdx.x - DFT_BLOCKS;
        const int which = bid2 >> 7;
        const int m0 = (bid2 & 127) * 64;
        const float* cb = which ? cbP : cbA;
        for (int e = tid; e < 4096; e += 256) {
            int c = e >> 6, d = e & 63;
            tile[c * 65 + d] = cb[(size_t)(m0 + c) * VQD + d];
        }
        __syncthreads();
        if (tid < 64) {
            double s = 0.0;
            for (int d2 = 0; d2 < 64; ++d2) { double v = (double)tile[tid * 65 + d2]; s += v * v; }
            inv[tid] = (float)(1.0 / sqrt(s));
            invnD[(size_t)which * NEMB + m0 + tid] = 1.0 / sqrt(s);
        }
        __syncthreads();
        for (int e = tid; e < 4096; e += 256) {
            int c = e >> 6, d = e & 63;
            float v = tile[c * 65 + d] * inv[c];
            unsigned short hb = f2bf(v);
            unsigned short lb = f2bf(v - bf2f(hb));
            size_t o = ((size_t)which * NEMB + m0 + c) * VQD + d;
            cbH[o] = hb; cbL[o] = lb;
        }
        return;
    }

    float*  xsT  = (float*)smem;                 // [n][r] stride 9
    float*  xpS  = (float*)(smem + 7200);        // [n][8], n=1..99
    float*  xmS  = (float*)(smem + 10400);
    float*  reS  = (float*)(smem + 13600);       // [k][8]
    float*  imS  = (float*)(smem + 16832);
    double* cisT = (double*)(smem + 13600);      // f64[101][2] = 1616 B, aliases reS (dead)
    float*  accS = (float*)(smem + 7200);        // proj partials, after xp/xm die
    const int r0 = blockIdx.x * 8;

    for (int e = tid; e < 8 * IN_DIM; e += 256) {
        int r = e / IN_DIM, n = e - r * IN_DIM;
        xsT[n * 9 + r] = x[(size_t)(r0 + r) * IN_DIM + n];
    }
    __syncthreads();

    // pair build in f32: xp = x[n]+x[200-n], xm = x[n]-x[200-n] (rounding ~2^-25, in budget)
    for (int e = tid; e < 99 * 8; e += 256) {
        int n = (e >> 3) + 1, r = e & 7;
        float a = xsT[n * 9 + r];
        float b = xsT[(IN_DIM - n) * 9 + r];
        xpS[n * 8 + r] = a + b;
        xmS[n * 8 + r] = a - b;
    }
    // cis table: one f64 sincos per k, computed once per block (2 wave-calls vs r18's 8)
    if (tid < FREQ) {
        double c, s;
        cis_exact(tid, c, s);
        cisT[tid * 2]     = c;
        cisT[tid * 2 + 1] = s;
    }
    __syncthreads();

    const int k = tid & 127, half = tid >> 7;
    double c1 = 1.0, s1 = 0.0, wc = 1.0, ws = 0.0;
    if (k < FREQ) {
        c1 = cisT[k * 2]; s1 = cisT[k * 2 + 1];
        if (!half) {                       // start at n=1: cis(k) — bitwise same as before
            wc = c1; ws = s1;
        } else {                           // start at n=51: cis(51k) = quarter(k&3)*cis(k), exact
            switch (k & 3) {
                case 0: wc =  c1; ws =  s1; break;   // *( 1, 0)
                case 1: wc =  s1; ws = -c1; break;   // *( 0,-1)
                case 2: wc = -c1; ws = -s1; break;   // *(-1, 0)
                default: wc = -s1; ws =  c1; break;  // *( 0, 1)
            }
        }
    }
    __syncthreads();   // seals cisT before half-1's reS stores (table now dead)

    float re[8], im[8];
    if (k < FREQ) {
#pragma unroll
        for (int r = 0; r < 8; ++r) { re[r] = 0.f; im[r] = 0.f; }
        if (half) {
            // singles n=0 (w=1) and n=100 (w=((-1)^k,+0)); im contribution exactly +-0 -> skip
            float sg = (k & 1) ? -1.f : 1.f;
#pragma unroll
            for (int r = 0; r < 8; ++r)
                re[r] = xsT[r] + sg * xsT[100 * 9 + r];
        }
        const int n0   = half ? 51 : 1;
        const int nEnd = half ? 100 : 51;            // half0: 1..50, half1: 51..99
        for (int n = n0; n < nEnd; ++n) {
            const float* xpn = xpS + n * 8;
            const float* xmn = xmS + n * 8;
            float wcf = (float)wc, wsf = (float)ws;
#pragma unroll
            for (int r = 0; r < 8; ++r) {
                re[r] = fmaf(xpn[r], wcf, re[r]);
                im[r] = fmaf(xmn[r], wsf, im[r]);
            }
            double nwc = fma(wc, c1, -ws * s1);
            double nws = fma(wc, s1,  ws * c1);
            wc = nwc; ws = nws;
        }
        if (half) {
#pragma unroll
            for (int r = 0; r < 8; ++r) { reS[k * 8 + r] = re[r]; imS[k * 8 + r] = im[r]; }
        }
    }
    __syncthreads();
    // combine halves in-place (each [k][r] owned by exactly one half-0 thread)
    if (half == 0 && k < FREQ) {
#pragma unroll
        for (int r = 0; r < 8; ++r) {
            re[r] += reS[k * 8 + r]; im[r] += imS[k * 8 + r];
            reS[k * 8 + r] = re[r];  imS[k * 8 + r] = im[r];
        }
    }
    __syncthreads();
    // amp/phase on ALL 256 threads, f32 fast path; rare exact-f64 fallback for small bins
    // (xsT still alive -> fallback recomputes the bin from the exact f32 inputs)
    for (int e = tid; e < FREQ * 8; e += 256) {
        float c = reS[e], s = imS[e];
        float a2 = fmaf(c, c, s * s);
        float ampv, phv;
        if (a2 >= 0.04f) {
            ampv = sqrtf(a2);
            phv  = atan2f(s, c);
        } else {
            const int kk = e >> 3, rr = e & 7;
            double sg = (kk & 1) ? -1.0 : 1.0;
            double reD = (double)xsT[rr] + sg * (double)xsT[100 * 9 + rr];
            double imD = 0.0;
            double cc1, ss1;
            cis_exact(kk, cc1, ss1);
            double twc = cc1, tws = ss1;             // w at n=1
            for (int n = 1; n < 100; ++n) {
                double a = (double)xsT[n * 9 + rr];
                double b = (double)xsT[(IN_DIM - n) * 9 + rr];
                reD = fma(a + b, twc, reD);
                imD = fma(a - b, tws, imD);
                double nwc = fma(twc, cc1, -tws * ss1);
                double nws = fma(twc, ss1,  tws * cc1);
                twc = nwc; tws = nws;
            }
            ampv = (float)sqrt(reD * reD + imD * imD);
            phv  = (float)atan2(imD, reD);
        }
        reS[e] = ampv; imS[e] = phv;
    }
    __syncthreads();

    // projection in f32: d = tid&63; which = amp/phase; grp splits kk range 51/50
    const int d = tid & 63, which = (tid >> 6) & 1, grp = tid >> 7;
    const float* proj = which ? projP : projA;
    const float* srcF = which ? imS : reS;          // [k][8], k-major
    float acc[8];
#pragma unroll
    for (int r = 0; r < 8; ++r) acc[r] = 0.f;
    const int kkA = grp ? 51 : 0;
    const int kkB = grp ? FREQ : 51;
    for (int kk = kkA; kk < kkB; ++kk) {
        float p = proj[kk * VQD + d];
#pragma unroll
        for (int r = 0; r < 8; ++r) acc[r] = fmaf(srcF[kk * 8 + r], p, acc[r]);
    }
    if (grp) {
#pragma unroll
        for (int r = 0; r < 8; ++r) accS[(tid & 127) * 8 + r] = acc[r];
    }
    __syncthreads();
    if (grp == 0) {
#pragma unroll
        for (int r = 0; r < 8; ++r) acc[r] += accS[tid * 8 + r];
#pragma unroll
        for (int r = 0; r < 8; ++r) {
            size_t rowi = (size_t)which * ROWS + r0 + r;
            float vf = acc[r];
            unsigned short hb = f2bf(vf);
            unsigned short lb = f2bf(vf - bf2f(hb));
            ftH[rowi * VQD + d] = hb;
            ftL[rowi * VQD + d] = lb;
            featD[rowi * VQD + d] = (double)acc[r];
        }
    }
}

// ---------------- 2. bf16x3 MFMA sim + top-2, DMA double-buffered prefetch ----------------
// (round-10 version, byte-identical: best measured; argmax is closed at ~154 us — MFMA
// pipe at the bf16x3 algorithmic floor, selection VALU near op-count floor, residual
// idle resisted 4 structural attacks)
#define MFMA(a, b, c) __builtin_amdgcn_mfma_f32_16x16x32_bf16(a, b, c, 0, 0, 0)
#define UPD(val, s) do { float _v = (val); \
    bool _c1 = _v > b1v[s]; bool _c2 = _v > b2v[s]; \
    b2v[s] = _c1 ? b1v[s] : (_c2 ? _v : b2v[s]); \
    b2i[s] = _c1 ? b1i[s] : (_c2 ? idx : b2i[s]); \
    b1v[s] = _c1 ? _v : b1v[s]; \
    b1i[s] = _c1 ? idx : b1i[s]; } while (0)

__global__ __launch_bounds__(256, 3) void argmax_kernel(
    const unsigned short* __restrict__ ftH, const unsigned short* __restrict__ ftL,
    const unsigned short* __restrict__ cbH, const unsigned short* __restrict__ cbL,
    int* __restrict__ pi1, int* __restrict__ pi2)
{
    __shared__ __align__(16) char lds[33792];
    const int tid = threadIdx.x;
    const int f = blockIdx.y, z = blockIdx.z;
    const int r0 = blockIdx.x * 128;
    const int w = tid >> 6, lane = tid & 63;
    const int q = lane >> 4, cl = lane & 15;

    const unsigned short* ftHb = ftH + (size_t)f * ROWS * VQD;
    const unsigned short* ftLb = ftL + (size_t)f * ROWS * VQD;
    const unsigned short* cbHb = cbH + (size_t)f * NEMB * VQD;
    const unsigned short* cbLb = cbL + (size_t)f * NEMB * VQD;

    short8 aH00, aH01, aH10, aH11, aL00, aL01, aL10, aL11;
    {
        const size_t baseA = (size_t)(r0 + w * 32 + cl) * VQD + q * 8;
        const size_t baseB = baseA + (size_t)16 * VQD;
        aH00 = *(const short8*)(ftHb + baseA);
        aH01 = *(const short8*)(ftHb + baseA + 32);
        aH10 = *(const short8*)(ftHb + baseB);
        aH11 = *(const short8*)(ftHb + baseB + 32);
        aL00 = *(const short8*)(ftLb + baseA);
        aL01 = *(const short8*)(ftLb + baseA + 32);
        aL10 = *(const short8*)(ftLb + baseB);
        aL11 = *(const short8*)(ftLb + baseB + 32);
    }

    float b1v[8], b2v[8]; int b1i[8], b2i[8];
#pragma unroll
    for (int s = 0; s < 8; ++s) { b1v[s] = -INFINITY; b2v[s] = -INFINITY; b1i[s] = 0; b2i[s] = 0; }

    const int cBase = tid >> 3;
    const int jel   = (((tid & 7) ^ (cBase & 7)) << 3);
    const unsigned short* gH = cbHb + (size_t)(z * 2048 + cBase) * VQD + jel;
    const unsigned short* gL = cbLb + (size_t)(z * 2048 + cBase) * VQD + jel;

    const int p0 = ((q ^ (cl & 7)) << 4);
    const int p1 = p0 ^ 64;

#pragma unroll
    for (int r = 0; r < 2; ++r) {
        const size_t gofs = (size_t)(32 * r) * VQD;
        GLOAD_LDS(gH + gofs, lds + w * 1024 + r * 4096);
        GLOAD_LDS(gL + gofs, lds + 8192 + w * 1024 + r * 4096);
    }

    for (int it = 0; it < 32; ++it) {
        __syncthreads();
        if (it < 31) {
            char* nbuf = lds + ((it + 1) & 1) * 16384;
            const size_t gbase = (size_t)((it + 1) * 64) * VQD;
#pragma unroll
            for (int r = 0; r < 2; ++r) {
                const size_t gofs = gbase + (size_t)(32 * r) * VQD;
                GLOAD_LDS(gH + gofs, nbuf + w * 1024 + r * 4096);
                GLOAD_LDS(gL + gofs, nbuf + 8192 + w * 1024 + r * 4096);
            }
        }

        const char* buf = lds + (it & 1) * 16384;
        const int cbase = z * 2048 + it * 64;
#pragma unroll
        for (int nt = 0; nt < 4; ++nt) {
            const char* row = buf + (nt * 16 + cl) * 128;
            short8 bH0 = *(const short8*)(row + p0);
            short8 bH1 = *(const short8*)(row + p1);
            short8 bL0 = *(const short8*)(row + 8192 + p0);
            short8 bL1 = *(const short8*)(row + 8192 + p1);

            floatx4 acc0 = {0.f, 0.f, 0.f, 0.f};
            floatx4 acc1 = {0.f, 0.f, 0.f, 0.f};
            acc0 = MFMA(aH00, bH0, acc0);  acc1 = MFMA(aH10, bH0, acc1);
            acc0 = MFMA(aH01, bH1, acc0);  acc1 = MFMA(aH11, bH1, acc1);
            acc0 = MFMA(aH00, bL0, acc0);  acc1 = MFMA(aH10, bL0, acc1);
            acc0 = MFMA(aH01, bL1, acc0);  acc1 = MFMA(aH11, bL1, acc1);
            acc0 = MFMA(aL00, bH0, acc0);  acc1 = MFMA(aL10, bH0, acc1);
            acc0 = MFMA(aL01, bH1, acc0);  acc1 = MFMA(aL11, bH1, acc1);

            const int idx = cbase + nt * 16 + cl;
#pragma unroll
            for (int i = 0; i < 4; ++i) { UPD(acc0[i], i); UPD(acc1[i], 4 + i); }
        }
    }

    __syncthreads();
    float* redv = (float*)lds;           // [128][33]
    int*   redi = (int*)(lds + 128 * 33 * 4);
#pragma unroll
    for (int s = 0; s < 8; ++s) {
        int rowl = w * 32 + ((s & 4) << 2) + q * 4 + (s & 3);   // +16 when s>=4
        int base = rowl * 33 + cl * 2;
        redv[base]     = b1v[s]; redi[base]     = b1i[s];
        redv[base + 1] = b2v[s]; redi[base + 1] = b2i[s];
    }
    __syncthreads();
    if (tid < 128) {
        float v1 = -INFINITY, v2 = -INFINITY; int i1 = 0x7fffffff, i2 = 0x7fffffff;
        for (int e = 0; e < 32; ++e) {
            float v = redv[tid * 33 + e]; int id = redi[tid * 33 + e];
            if (v > v1 || (v == v1 && id < i1)) { v2 = v1; i2 = i1; v1 = v; i1 = id; }
            else if (v > v2 || (v == v2 && id < i2)) { v2 = v; i2 = id; }
        }
        size_t p = ((size_t)(f * 4 + z)) * ROWS + r0 + tid;
        pi1[p] = i1; pi2[p] = i2;
    }
}

// ---------------- 3. f64 rescore of the 8 candidates/row ----------------
// r19: 8-lanes-per-candidate restructure. Old: 8 cands x 6 shfl levels x 2 bpermute
// = 96 bpermutes/wave through the per-CU LDS pipe (~35-45 us across 152 waves/CU).
// New: lane = cand*8 + dpart; 8-elem f64 partial dot per lane, 3-level xor reduce
// within the 8-lane group, then 3-level (sim,idx) argmax across groups = 15 bpermutes.
// Tie -> min idx (candidate idxs are distinct across chunks); f64 sum order changes
// at ~1e-16 relative, far below inter-row sim margins.
__global__ __launch_bounds__(256) void rescore_kernel(
    const double* __restrict__ featD, const double* __restrict__ invnD,
    const float* __restrict__ cbA, const float* __restrict__ cbP,
    const int* __restrict__ pi1, const int* __restrict__ pi2,
    int* __restrict__ out)
{
    const int tid = threadIdx.x;
    const int lane = tid & 63, wave = tid >> 6;
    const int task = blockIdx.x * 4 + wave;           // 0 .. 2*ROWS-1
    const int f = task / ROWS;
    const int row = task - f * ROWS;
    const float* cb = f ? cbP : cbA;

    const int c  = lane >> 3;        // candidate 0..7
    const int dp = (lane & 7) * 8;   // d-slice base

    const int zz = c >> 1;
    const size_t p = ((size_t)(f * 4 + zz)) * ROWS + row;
    const int idx = (c & 1) ? pi2[p] : pi1[p];

    const double* fr = featD + ((size_t)f * ROWS + row) * VQD + dp;
    const float*  cr = cb + (size_t)idx * VQD + dp;
    double t = 0.0;
#pragma unroll
    for (int j = 0; j < 8; ++j) t = fma(fr[j], (double)cr[j], t);
    t += __shfl_xor(t, 1, 64);
    t += __shfl_xor(t, 2, 64);
    t += __shfl_xor(t, 4, 64);
    double bv = t * invnD[(size_t)f * NEMB + idx];
    int    bi = idx;
#pragma unroll
    for (int m = 8; m <= 32; m <<= 1) {
        double ov = __shfl_xor(bv, m, 64);
        int    oi = __shfl_xor(bi, m, 64);
        if (ov > bv || (ov == bv && oi < bi)) { bv = ov; bi = oi; }
    }
    if (lane == 0) out[task] = bi;
}

// ---------------- launch ----------------
extern "C" void kernel_launch(void* const* d_in, const int* in_sizes, int n_in,
                              void* d_out, int out_size, void* d_ws, size_t ws_size,
                              hipStream_t stream)
{
    const float* x     = (const float*)d_in[0];
    const float* projA = (const float*)d_in[1];
    const float* projP = (const float*)d_in[2];
    const float* cbA   = (const float*)d_in[3];
    const float* cbP   = (const float*)d_in[4];

    char* ws = (char*)d_ws;
    unsigned short* ftH   = (unsigned short*)(ws + OFF_FTH);
    unsigned short* ftL   = (unsigned short*)(ws + OFF_FTL);
    unsigned short* cbHp  = (unsigned short*)(ws + OFF_CBH);
    unsigned short* cbLp  = (unsigned short*)(ws + OFF_CBL);
    double*         featD = (double*)(ws + OFF_FD);
    double*         invnD = (double*)(ws + OFF_INV);
    int*            pi1   = (int*)(ws + OFF_PI1);
    int*            pi2   = (int*)(ws + OFF_PI2);

    dft_cb_kernel<<<DFT_BLOCKS + 256, 256, 0, stream>>>(
        x, projA, projP, cbA, cbP, ftH, ftL, featD, cbHp, cbLp, invnD);
    argmax_kernel<<<dim3(ROWS / 128, 2, 4), 256, 0, stream>>>(ftH, ftL, cbHp, cbLp, pi1, pi2);
    rescore_kernel<<<(2 * ROWS) / 4, 256, 0, stream>>>(featD, invnD, cbA, cbP, pi1, pi2, (int*)d_out);
}